// Round 1
// baseline (1012.906 us; speedup 1.0000x reference)
//
#include <hip/hip_runtime.h>

#define HDIM 1024
#define TLEN 2048
#define NBATCH 16

// ---------- Z = X*X (1024^3 fp32, 64x64 tile, 4x4 per thread) ----------
__global__ __launch_bounds__(256) void gemm_sq(const float* __restrict__ X,
                                               float* __restrict__ Z) {
  const int N = HDIM;
  __shared__ float As[16][64];  // As[k][m] (transposed A tile)
  __shared__ float Bs[16][64];  // Bs[k][n]
  const int tid = threadIdx.x;
  const int tx = tid & 15;        // n-dir (4 cols each)
  const int ty = tid >> 4;        // m-dir (4 rows each)
  const int bm = blockIdx.y * 64;
  const int bn = blockIdx.x * 64;
  // staging maps
  const int ar  = tid >> 2;          // 0..63  A-tile row
  const int ac4 = (tid & 3) << 2;    // 0,4,8,12
  const int br  = tid >> 4;          // 0..15  B-tile row (k)
  const int bc4 = (tid & 15) << 2;   // 0..60

  float acc[4][4] = {{0.f,0.f,0.f,0.f},{0.f,0.f,0.f,0.f},
                     {0.f,0.f,0.f,0.f},{0.f,0.f,0.f,0.f}};

  // preload first tile into regs (reg double-buffer: next-tile load overlaps compute)
  float4 av = *(const float4*)&X[(bm + ar) * N + ac4];
  float4 bv = *(const float4*)&X[br * N + bn + bc4];

  for (int k0 = 0; k0 < N; k0 += 16) {
    __syncthreads();  // previous tile's compute done
    As[ac4 + 0][ar] = av.x;
    As[ac4 + 1][ar] = av.y;
    As[ac4 + 2][ar] = av.z;
    As[ac4 + 3][ar] = av.w;
    *(float4*)&Bs[br][bc4] = bv;
    __syncthreads();
    if (k0 + 16 < N) {
      av = *(const float4*)&X[(bm + ar) * N + (k0 + 16) + ac4];
      bv = *(const float4*)&X[(k0 + 16 + br) * N + bn + bc4];
    }
#pragma unroll
    for (int kk = 0; kk < 16; ++kk) {
      float4 a = *(const float4*)&As[kk][ty << 2];
      float4 b = *(const float4*)&Bs[kk][tx << 2];
      float aa[4] = {a.x, a.y, a.z, a.w};
      float bb[4] = {b.x, b.y, b.z, b.w};
#pragma unroll
      for (int i = 0; i < 4; ++i)
#pragma unroll
        for (int j = 0; j < 4; ++j) acc[i][j] += aa[i] * bb[j];
    }
  }
#pragma unroll
  for (int i = 0; i < 4; ++i) {
    float4 o = make_float4(acc[i][0], acc[i][1], acc[i][2], acc[i][3]);
    *(float4*)&Z[(bm + (ty << 2) + i) * N + bn + (tx << 2)] = o;
  }
}

// ---------- init: V col0 = B, U row0 = C ----------
__global__ void initVU(const float* __restrict__ Bv, const float* __restrict__ Cv,
                       float* __restrict__ Vc, float* __restrict__ U) {
  int i = blockIdx.x * blockDim.x + threadIdx.x;
  if (i < HDIM) {
    Vc[i] = Bv[i];  // V column-major: col 0
    U[i]  = Cv[i];  // U row-major: row 0
  }
}

// ---------- V doubling: Vdst[n][:] = P * Vsrc[n][:], n=0..NCOLS-1 ----------
// One wave per output row m (1024 waves). A (P) row-major, V column-major.
template <int NCOLS>
__global__ __launch_bounds__(256) void wavedotN(const float* __restrict__ P,
                                                const float* __restrict__ Vsrc,
                                                float* __restrict__ Vdst) {
  int w = (blockIdx.x * blockDim.x + threadIdx.x) >> 6;  // 0..1023 (row m)
  int lane = threadIdx.x & 63;
  if (w >= HDIM) return;
  float acc[NCOLS];
#pragma unroll
  for (int n = 0; n < NCOLS; ++n) acc[n] = 0.f;
  for (int k = lane; k < HDIM; k += 64) {
    float a = P[w * HDIM + k];
#pragma unroll
    for (int n = 0; n < NCOLS; ++n) acc[n] += a * Vsrc[n * HDIM + k];
  }
#pragma unroll
  for (int n = 0; n < NCOLS; ++n) {
    float s = acc[n];
    for (int off = 32; off; off >>= 1) s += __shfl_down(s, off);
    if (lane == 0) Vdst[n * HDIM + w] = s;
  }
}

// ---------- U doubling: Udst[m,:] = U[m,:] * P  (m = blockIdx.y) ----------
__global__ __launch_bounds__(256) void rowgemm(const float* __restrict__ U,
                                               const float* __restrict__ P,
                                               float* __restrict__ Udst) {
  int n = blockIdx.x * blockDim.x + threadIdx.x;  // column, coalesced on P
  int m = blockIdx.y;
  float s = 0.f;
  for (int k = 0; k < HDIM; ++k) s += U[m * HDIM + k] * P[k * HDIM + n];
  Udst[m * HDIM + n] = s;
}

// ---------- K[i*32+j] = U row j . V col i  (32x64 outputs, one wave each) ----------
__global__ __launch_bounds__(256) void wavedotK(const float* __restrict__ U,
                                                const float* __restrict__ Vc,
                                                float* __restrict__ Km) {
  int w = (blockIdx.x * blockDim.x + threadIdx.x) >> 6;  // 0..2047
  int lane = threadIdx.x & 63;
  if (w >= 32 * 64) return;
  int m = w >> 6;        // U row j
  int n = w & 63;        // V col i
  float s = 0.f;
  for (int k = lane; k < HDIM; k += 64) s += U[m * HDIM + k] * Vc[n * HDIM + k];
  for (int off = 32; off; off >>= 1) s += __shfl_down(s, off);
  if (lane == 0) Km[n * 32 + m] = s;  // k_{64*m+n} stored at [n*32+m]
}

// ---------- causal conv: y[b,t] = D*u[b,t] + sum_{m<=t} k_m u[b,t-m] ----------
__global__ __launch_bounds__(256) void convk(const float* __restrict__ u,
                                             const float* __restrict__ Km,
                                             const float* __restrict__ Dv,
                                             float* __restrict__ y) {
  int t = blockIdx.x * blockDim.x + threadIdx.x;  // 0..2047
  int b = blockIdx.y;
  const float* ub = u + b * TLEN;
  float s = Dv[0] * ub[t];
  for (int m = 0; m <= t; ++m) {
    // k_m = C A^m B ; m = 64*j + i stored at Km[i*32 + j]
    float kv = Km[((m & 63) << 5) + (m >> 6)];
    s += kv * ub[t - m];
  }
  y[b * TLEN + t] = s;
}

extern "C" void kernel_launch(void* const* d_in, const int* in_sizes, int n_in,
                              void* d_out, int out_size, void* d_ws, size_t ws_size,
                              hipStream_t stream) {
  const float* u  = (const float*)d_in[0];  // (16,2048,1)
  const float* A  = (const float*)d_in[1];  // (1024,1024)
  const float* Bv = (const float*)d_in[2];  // (1024,1)
  const float* Cv = (const float*)d_in[3];  // (1,1024)
  const float* Dv = (const float*)d_in[4];  // (1,)
  float* out = (float*)d_out;

  float* P0 = (float*)d_ws;            // 4 MB
  float* P1 = P0 + HDIM * HDIM;        // 4 MB
  float* Vc = P1 + HDIM * HDIM;        // 64 cols x 1024, column-major
  float* U  = Vc + 64 * HDIM;          // 32 rows x 1024, row-major
  float* Km = U + 32 * HDIM;           // 2048 scalars

  dim3 gsq(16, 16);

  initVU<<<dim3(4), 256, 0, stream>>>(Bv, Cv, Vc, U);
  // V col 1 = A * V col 0   (uses A^1 = input A)
  wavedotN<1><<<dim3(256), 256, 0, stream>>>(A, Vc, Vc + 1 * HDIM);

  gemm_sq<<<gsq, 256, 0, stream>>>(A, P0);                       // A^2
  wavedotN<2><<<dim3(256), 256, 0, stream>>>(P0, Vc, Vc + 2 * HDIM);
  gemm_sq<<<gsq, 256, 0, stream>>>(P0, P1);                      // A^4
  wavedotN<4><<<dim3(256), 256, 0, stream>>>(P1, Vc, Vc + 4 * HDIM);
  gemm_sq<<<gsq, 256, 0, stream>>>(P1, P0);                      // A^8
  wavedotN<8><<<dim3(256), 256, 0, stream>>>(P0, Vc, Vc + 8 * HDIM);
  gemm_sq<<<gsq, 256, 0, stream>>>(P0, P1);                      // A^16
  wavedotN<16><<<dim3(256), 256, 0, stream>>>(P1, Vc, Vc + 16 * HDIM);
  gemm_sq<<<gsq, 256, 0, stream>>>(P1, P0);                      // A^32
  wavedotN<32><<<dim3(256), 256, 0, stream>>>(P0, Vc, Vc + 32 * HDIM);

  gemm_sq<<<gsq, 256, 0, stream>>>(P0, P1);                      // A^64
  rowgemm<<<dim3(4, 1), 256, 0, stream>>>(U, P1, U + 1 * HDIM);  // rows 1:2
  gemm_sq<<<gsq, 256, 0, stream>>>(P1, P0);                      // A^128
  rowgemm<<<dim3(4, 2), 256, 0, stream>>>(U, P0, U + 2 * HDIM);  // rows 2:4
  gemm_sq<<<gsq, 256, 0, stream>>>(P0, P1);                      // A^256
  rowgemm<<<dim3(4, 4), 256, 0, stream>>>(U, P1, U + 4 * HDIM);  // rows 4:8
  gemm_sq<<<gsq, 256, 0, stream>>>(P1, P0);                      // A^512
  rowgemm<<<dim3(4, 8), 256, 0, stream>>>(U, P0, U + 8 * HDIM);  // rows 8:16
  gemm_sq<<<gsq, 256, 0, stream>>>(P0, P1);                      // A^1024
  rowgemm<<<dim3(4, 16), 256, 0, stream>>>(U, P1, U + 16 * HDIM);// rows 16:32

  wavedotK<<<dim3(512), 256, 0, stream>>>(U, Vc, Km);
  convk<<<dim3(TLEN / 256, NBATCH), 256, 0, stream>>>(u, Km, Dv, out);
}

// Round 2
// 496.678 us; speedup vs baseline: 2.0394x; 2.0394x over previous
//
#include <hip/hip_runtime.h>

#define HDIM 1024
#define TLEN 2048
#define NBATCH 16

typedef short bf16x8 __attribute__((ext_vector_type(8)));
typedef float floatx4 __attribute__((ext_vector_type(4)));
typedef unsigned short ushort_t;

__device__ __forceinline__ ushort_t f2bf(float x) {
  unsigned u = __float_as_uint(x);
  unsigned r = (u + 0x7FFFu + ((u >> 16) & 1u)) >> 16;
  return (ushort_t)r;
}
__device__ __forceinline__ float bf2f(ushort_t h) {
  return __uint_as_float(((unsigned)h) << 16);
}

#define LSTR 40     // staged row stride in bf16 elems (32 + 8 pad -> 80B, 16B-aligned)
#define TSTR 71     // epilogue transpose stride (odd -> spreads banks)

// ---------------- split input A into bf16 h/m/l + transposed copies ----------------
__global__ __launch_bounds__(256) void splitA(const float* __restrict__ A,
    ushort_t* __restrict__ Ah, ushort_t* __restrict__ Am, ushort_t* __restrict__ Al,
    ushort_t* __restrict__ ATh, ushort_t* __restrict__ ATm, ushort_t* __restrict__ ATl) {
  __shared__ ushort_t Lt[3 * 64 * TSTR];
  const int row0 = blockIdx.y * 64, col0 = blockIdx.x * 64;
  const int tid = threadIdx.x;
  const int r = tid >> 2, q = tid & 3;  // row r, cols q*16..+15
  ushort_t hs[16], ms[16], ls[16];
#pragma unroll
  for (int c4 = 0; c4 < 4; ++c4) {
    float4 a = *(const float4*)&A[(row0 + r) * HDIM + col0 + q * 16 + c4 * 4];
    float av[4] = {a.x, a.y, a.z, a.w};
#pragma unroll
    for (int i = 0; i < 4; ++i) {
      float z = av[i];
      ushort_t h = f2bf(z); float r1 = z - bf2f(h);
      ushort_t mq = f2bf(r1); float r2 = r1 - bf2f(mq);
      ushort_t lq = f2bf(r2);
      hs[c4 * 4 + i] = h; ms[c4 * 4 + i] = mq; ls[c4 * 4 + i] = lq;
    }
  }
  size_t go = (size_t)(row0 + r) * HDIM + col0 + q * 16;
  *(uint4*)&Ah[go] = ((uint4*)hs)[0]; *(uint4*)&Ah[go + 8] = ((uint4*)hs)[1];
  *(uint4*)&Am[go] = ((uint4*)ms)[0]; *(uint4*)&Am[go + 8] = ((uint4*)ms)[1];
  *(uint4*)&Al[go] = ((uint4*)ls)[0]; *(uint4*)&Al[go + 8] = ((uint4*)ls)[1];
#pragma unroll
  for (int i = 0; i < 16; ++i) {
    int c = q * 16 + i;
    Lt[0 * 64 * TSTR + r * TSTR + c] = hs[i];
    Lt[1 * 64 * TSTR + r * TSTR + c] = ms[i];
    Lt[2 * 64 * TSTR + r * TSTR + c] = ls[i];
  }
  __syncthreads();
  // transposed write: thread handles XT row (col0+c), cols row0+q*16..+15
  const int c = tid >> 2, q2 = tid & 3;
  ushort_t* dsts[3] = {ATh, ATm, ATl};
#pragma unroll
  for (int s = 0; s < 3; ++s) {
    ushort_t tmp[16];
#pragma unroll
    for (int rr = 0; rr < 16; ++rr) tmp[rr] = Lt[s * 64 * TSTR + (q2 * 16 + rr) * TSTR + c];
    size_t gt = (size_t)(col0 + c) * HDIM + row0 + q2 * 16;
    *(uint4*)&dsts[s][gt] = ((uint4*)tmp)[0];
    *(uint4*)&dsts[s][gt + 8] = ((uint4*)tmp)[1];
  }
}

// ---------------- Z = X*X via bf16 3-split MFMA (6 cross terms) ----------------
// inputs: row-major splits (A-frags) + transposed splits (B-frags)
// outputs: fp32 Z + row-major splits + transposed splits
__global__ __launch_bounds__(256, 1) void sq_mfma(
    const ushort_t* __restrict__ Xh, const ushort_t* __restrict__ Xm,
    const ushort_t* __restrict__ Xl,
    const ushort_t* __restrict__ XTh, const ushort_t* __restrict__ XTm,
    const ushort_t* __restrict__ XTl,
    float* __restrict__ Z,
    ushort_t* __restrict__ Zh, ushort_t* __restrict__ Zm, ushort_t* __restrict__ Zl,
    ushort_t* __restrict__ ZTh, ushort_t* __restrict__ ZTm, ushort_t* __restrict__ ZTl) {
  __shared__ ushort_t sm[6 * 64 * LSTR];  // 30720 B; reused for epilogue transpose
  const int AH = 0, AM = 64 * LSTR, AL = 2 * 64 * LSTR;
  const int BH = 3 * 64 * LSTR, BM = 4 * 64 * LSTR, BL = 5 * 64 * LSTR;
  const int tid = threadIdx.x;
  const int w = tid >> 6, l = tid & 63, li = l & 15, quad = l >> 4;
  const int row0 = blockIdx.y * 64, col0 = blockIdx.x * 64;
  const int sr = tid >> 2, sq4 = tid & 3;  // staging: row sr, 8-elem quarter sq4

  floatx4 acc0 = {0.f, 0.f, 0.f, 0.f}, acc1 = acc0, acc2 = acc0, acc3 = acc0;

  const int aoff = (w * 16 + li) * LSTR + quad * 8;
  const int b0o = (0 * 16 + li) * LSTR + quad * 8;
  const int b1o = (1 * 16 + li) * LSTR + quad * 8;
  const int b2o = (2 * 16 + li) * LSTR + quad * 8;
  const int b3o = (3 * 16 + li) * LSTR + quad * 8;
  const int soff = sr * LSTR + sq4 * 8;
  const size_t gA = (size_t)(row0 + sr) * HDIM + sq4 * 8;
  const size_t gB = (size_t)(col0 + sr) * HDIM + sq4 * 8;

  uint4 pa0 = *(const uint4*)&Xh[gA], pa1 = *(const uint4*)&Xm[gA], pa2 = *(const uint4*)&Xl[gA];
  uint4 pb0 = *(const uint4*)&XTh[gB], pb1 = *(const uint4*)&XTm[gB], pb2 = *(const uint4*)&XTl[gB];

  for (int k0 = 0; k0 < HDIM; k0 += 32) {
    __syncthreads();
    *(uint4*)&sm[AH + soff] = pa0;
    *(uint4*)&sm[AM + soff] = pa1;
    *(uint4*)&sm[AL + soff] = pa2;
    *(uint4*)&sm[BH + soff] = pb0;
    *(uint4*)&sm[BM + soff] = pb1;
    *(uint4*)&sm[BL + soff] = pb2;
    __syncthreads();
    if (k0 + 32 < HDIM) {
      pa0 = *(const uint4*)&Xh[gA + k0 + 32];
      pa1 = *(const uint4*)&Xm[gA + k0 + 32];
      pa2 = *(const uint4*)&Xl[gA + k0 + 32];
      pb0 = *(const uint4*)&XTh[gB + k0 + 32];
      pb1 = *(const uint4*)&XTm[gB + k0 + 32];
      pb2 = *(const uint4*)&XTl[gB + k0 + 32];
    }
    bf16x8 ah = *(const bf16x8*)&sm[AH + aoff];
    bf16x8 am = *(const bf16x8*)&sm[AM + aoff];
    bf16x8 al = *(const bf16x8*)&sm[AL + aoff];
    {
      bf16x8 bh = *(const bf16x8*)&sm[BH + b0o];
      bf16x8 bm = *(const bf16x8*)&sm[BM + b0o];
      bf16x8 bl = *(const bf16x8*)&sm[BL + b0o];
      acc0 = __builtin_amdgcn_mfma_f32_16x16x32_bf16(ah, bh, acc0, 0, 0, 0);
      acc0 = __builtin_amdgcn_mfma_f32_16x16x32_bf16(ah, bm, acc0, 0, 0, 0);
      acc0 = __builtin_amdgcn_mfma_f32_16x16x32_bf16(am, bh, acc0, 0, 0, 0);
      acc0 = __builtin_amdgcn_mfma_f32_16x16x32_bf16(am, bm, acc0, 0, 0, 0);
      acc0 = __builtin_amdgcn_mfma_f32_16x16x32_bf16(ah, bl, acc0, 0, 0, 0);
      acc0 = __builtin_amdgcn_mfma_f32_16x16x32_bf16(al, bh, acc0, 0, 0, 0);
    }
    {
      bf16x8 bh = *(const bf16x8*)&sm[BH + b1o];
      bf16x8 bm = *(const bf16x8*)&sm[BM + b1o];
      bf16x8 bl = *(const bf16x8*)&sm[BL + b1o];
      acc1 = __builtin_amdgcn_mfma_f32_16x16x32_bf16(ah, bh, acc1, 0, 0, 0);
      acc1 = __builtin_amdgcn_mfma_f32_16x16x32_bf16(ah, bm, acc1, 0, 0, 0);
      acc1 = __builtin_amdgcn_mfma_f32_16x16x32_bf16(am, bh, acc1, 0, 0, 0);
      acc1 = __builtin_amdgcn_mfma_f32_16x16x32_bf16(am, bm, acc1, 0, 0, 0);
      acc1 = __builtin_amdgcn_mfma_f32_16x16x32_bf16(ah, bl, acc1, 0, 0, 0);
      acc1 = __builtin_amdgcn_mfma_f32_16x16x32_bf16(al, bh, acc1, 0, 0, 0);
    }
    {
      bf16x8 bh = *(const bf16x8*)&sm[BH + b2o];
      bf16x8 bm = *(const bf16x8*)&sm[BM + b2o];
      bf16x8 bl = *(const bf16x8*)&sm[BL + b2o];
      acc2 = __builtin_amdgcn_mfma_f32_16x16x32_bf16(ah, bh, acc2, 0, 0, 0);
      acc2 = __builtin_amdgcn_mfma_f32_16x16x32_bf16(ah, bm, acc2, 0, 0, 0);
      acc2 = __builtin_amdgcn_mfma_f32_16x16x32_bf16(am, bh, acc2, 0, 0, 0);
      acc2 = __builtin_amdgcn_mfma_f32_16x16x32_bf16(am, bm, acc2, 0, 0, 0);
      acc2 = __builtin_amdgcn_mfma_f32_16x16x32_bf16(ah, bl, acc2, 0, 0, 0);
      acc2 = __builtin_amdgcn_mfma_f32_16x16x32_bf16(al, bh, acc2, 0, 0, 0);
    }
    {
      bf16x8 bh = *(const bf16x8*)&sm[BH + b3o];
      bf16x8 bm = *(const bf16x8*)&sm[BM + b3o];
      bf16x8 bl = *(const bf16x8*)&sm[BL + b3o];
      acc3 = __builtin_amdgcn_mfma_f32_16x16x32_bf16(ah, bh, acc3, 0, 0, 0);
      acc3 = __builtin_amdgcn_mfma_f32_16x16x32_bf16(ah, bm, acc3, 0, 0, 0);
      acc3 = __builtin_amdgcn_mfma_f32_16x16x32_bf16(am, bh, acc3, 0, 0, 0);
      acc3 = __builtin_amdgcn_mfma_f32_16x16x32_bf16(am, bm, acc3, 0, 0, 0);
      acc3 = __builtin_amdgcn_mfma_f32_16x16x32_bf16(ah, bl, acc3, 0, 0, 0);
      acc3 = __builtin_amdgcn_mfma_f32_16x16x32_bf16(al, bh, acc3, 0, 0, 0);
    }
  }

  // ---- epilogue: write fp32 Z, row-major splits, and LDS-transposed splits ----
  __syncthreads();  // all waves done with staging LDS
  floatx4 accs[4] = {acc0, acc1, acc2, acc3};
#pragma unroll
  for (int j = 0; j < 4; ++j) {
#pragma unroll
    for (int e = 0; e < 4; ++e) {
      float z = accs[j][e];
      int rl = w * 16 + quad * 4 + e;
      int cl = j * 16 + li;
      size_t go = (size_t)(row0 + rl) * HDIM + col0 + cl;
      Z[go] = z;
      ushort_t h = f2bf(z); float r1 = z - bf2f(h);
      ushort_t mq = f2bf(r1); float r2 = r1 - bf2f(mq);
      ushort_t lq = f2bf(r2);
      Zh[go] = h; Zm[go] = mq; Zl[go] = lq;
      sm[0 * 64 * TSTR + rl * TSTR + cl] = h;
      sm[1 * 64 * TSTR + rl * TSTR + cl] = mq;
      sm[2 * 64 * TSTR + rl * TSTR + cl] = lq;
    }
  }
  __syncthreads();
  const int c = tid >> 2, q2 = tid & 3;
  ushort_t* dsts[3] = {ZTh, ZTm, ZTl};
#pragma unroll
  for (int s = 0; s < 3; ++s) {
    ushort_t tmp[16];
#pragma unroll
    for (int rr = 0; rr < 16; ++rr) tmp[rr] = sm[s * 64 * TSTR + (q2 * 16 + rr) * TSTR + c];
    size_t gt = (size_t)(col0 + c) * HDIM + row0 + q2 * 16;
    *(uint4*)&dsts[s][gt] = ((uint4*)tmp)[0];
    *(uint4*)&dsts[s][gt + 8] = ((uint4*)tmp)[1];
  }
}

// ---------------- init: V col0 = B, U row0 = C, zero U rows 1..31 ----------------
__global__ void initVU(const float* __restrict__ Bv, const float* __restrict__ Cv,
                       float* __restrict__ Vc, float* __restrict__ U) {
  int i = blockIdx.x * blockDim.x + threadIdx.x;
  if (i < HDIM) {
    Vc[i] = Bv[i];
    U[i] = Cv[i];
  } else if (i < 32 * HDIM) {
    U[i] = 0.f;
  }
}

// ---------------- V doubling: Vdst[n][:] = P * Vsrc[n][:] ----------------
template <int NCOLS>
__global__ __launch_bounds__(256) void wavedotN(const float* __restrict__ P,
                                                const float* __restrict__ Vsrc,
                                                float* __restrict__ Vdst) {
  int wv = (blockIdx.x * blockDim.x + threadIdx.x) >> 6;
  int lane = threadIdx.x & 63;
  if (wv >= HDIM) return;
  float acc[NCOLS];
#pragma unroll
  for (int n = 0; n < NCOLS; ++n) acc[n] = 0.f;
  for (int k = lane; k < HDIM; k += 64) {
    float a = P[wv * HDIM + k];
#pragma unroll
    for (int n = 0; n < NCOLS; ++n) acc[n] += a * Vsrc[n * HDIM + k];
  }
#pragma unroll
  for (int n = 0; n < NCOLS; ++n) {
    float s = acc[n];
    for (int off = 32; off; off >>= 1) s += __shfl_down(s, off);
    if (lane == 0) Vdst[n * HDIM + wv] = s;
  }
}

// ---------------- U doubling (k-split + atomics): Udst[m] += U[m] * P[kchunk] ----------------
__global__ __launch_bounds__(256) void rowgemm2(const float* __restrict__ U,
                                                const float* __restrict__ P,
                                                float* __restrict__ Udst) {
  const int m = blockIdx.y;
  const int k0 = blockIdx.z * 128;
  const int n4 = threadIdx.x * 4;
  const float* Urow = U + (size_t)m * HDIM;
  float4 s = make_float4(0.f, 0.f, 0.f, 0.f);
  for (int k = k0; k < k0 + 128; ++k) {
    float uv = Urow[k];
    float4 p = *(const float4*)&P[(size_t)k * HDIM + n4];
    s.x += uv * p.x; s.y += uv * p.y; s.z += uv * p.z; s.w += uv * p.w;
  }
  float* d = Udst + (size_t)m * HDIM + n4;
  atomicAdd(&d[0], s.x); atomicAdd(&d[1], s.y);
  atomicAdd(&d[2], s.z); atomicAdd(&d[3], s.w);
}

// ---------------- K[m] = U row (m>>6) . V col (m&63), natural order ----------------
__global__ __launch_bounds__(256) void wavedotK(const float* __restrict__ U,
                                                const float* __restrict__ Vc,
                                                float* __restrict__ Km) {
  int wv = (blockIdx.x * blockDim.x + threadIdx.x) >> 6;
  int lane = threadIdx.x & 63;
  if (wv >= 32 * 64) return;
  int mr = wv >> 6;
  int nc = wv & 63;
  float s = 0.f;
  for (int k = lane; k < HDIM; k += 64) s += U[mr * HDIM + k] * Vc[nc * HDIM + k];
  for (int off = 32; off; off >>= 1) s += __shfl_down(s, off);
  if (lane == 0) Km[wv] = s;
}

// ---------------- causal conv, LDS-tiled ----------------
__global__ __launch_bounds__(256) void convk2(const float* __restrict__ u,
                                              const float* __restrict__ Km,
                                              const float* __restrict__ Dv,
                                              float* __restrict__ y) {
  __shared__ float ks[256];
  __shared__ float us[512];
  const int tt = threadIdx.x;
  const int t0 = blockIdx.x * 256;
  const int b = blockIdx.y;
  const float* ub = u + (size_t)b * TLEN;
  const int t = t0 + tt;
  float s = Dv[0] * ub[t];
  for (int mc = 0; mc <= t0; mc += 256) {
    __syncthreads();
    ks[tt] = Km[mc + tt];
    int w0 = t0 - mc - 255;
    int g0 = w0 + tt;
    us[tt] = (g0 >= 0) ? ub[g0] : 0.f;
    int g1 = w0 + 256 + tt;
    us[256 + tt] = (g1 < TLEN) ? ub[g1] : 0.f;
    __syncthreads();
    if (mc < t0) {
#pragma unroll 4
      for (int r = 0; r < 256; r += 4) {
        float4 kv = *(const float4*)&ks[r];
        s += kv.x * us[tt - r + 255];
        s += kv.y * us[tt - r + 254];
        s += kv.z * us[tt - r + 253];
        s += kv.w * us[tt - r + 252];
      }
    } else {
      for (int r = 0; r <= tt; ++r) s += ks[r] * us[tt - r + 255];
    }
  }
  y[(size_t)b * TLEN + t] = s;
}

extern "C" void kernel_launch(void* const* d_in, const int* in_sizes, int n_in,
                              void* d_out, int out_size, void* d_ws, size_t ws_size,
                              hipStream_t stream) {
  const float* u  = (const float*)d_in[0];
  const float* A  = (const float*)d_in[1];
  const float* Bv = (const float*)d_in[2];
  const float* Cv = (const float*)d_in[3];
  const float* Dv = (const float*)d_in[4];
  float* out = (float*)d_out;

  char* wsb = (char*)d_ws;
  float* Pz = (float*)wsb;                 // 4 MB fp32 power matrix (reused)
  size_t off = (size_t)4 << 20;
  ushort_t* S[2][6];
  for (int s = 0; s < 2; ++s)
    for (int a = 0; a < 6; ++a) { S[s][a] = (ushort_t*)(wsb + off); off += (size_t)2 << 20; }
  float* Vc = (float*)(wsb + off); off += 64 * HDIM * 4;
  float* U  = (float*)(wsb + off); off += 32 * HDIM * 4;
  float* Km = (float*)(wsb + off); off += TLEN * 4;

  dim3 gsq(16, 16);
  int cur = 0;

  initVU<<<dim3(128), 256, 0, stream>>>(Bv, Cv, Vc, U);
  splitA<<<gsq, 256, 0, stream>>>(A, S[0][0], S[0][1], S[0][2], S[0][3], S[0][4], S[0][5]);
  wavedotN<1><<<dim3(256), 256, 0, stream>>>(A, Vc, Vc + 1 * HDIM);

  // powers 2..32: feed V doubling
  const int vn[5] = {2, 4, 8, 16, 32};
  for (int i = 0; i < 5; ++i) {
    int nxt = cur ^ 1;
    sq_mfma<<<gsq, 256, 0, stream>>>(S[cur][0], S[cur][1], S[cur][2], S[cur][3], S[cur][4], S[cur][5],
                                     Pz,
                                     S[nxt][0], S[nxt][1], S[nxt][2], S[nxt][3], S[nxt][4], S[nxt][5]);
    switch (vn[i]) {
      case 2:  wavedotN<2><<<dim3(256), 256, 0, stream>>>(Pz, Vc, Vc + 2 * HDIM); break;
      case 4:  wavedotN<4><<<dim3(256), 256, 0, stream>>>(Pz, Vc, Vc + 4 * HDIM); break;
      case 8:  wavedotN<8><<<dim3(256), 256, 0, stream>>>(Pz, Vc, Vc + 8 * HDIM); break;
      case 16: wavedotN<16><<<dim3(256), 256, 0, stream>>>(Pz, Vc, Vc + 16 * HDIM); break;
      case 32: wavedotN<32><<<dim3(256), 256, 0, stream>>>(Pz, Vc, Vc + 32 * HDIM); break;
    }
    cur = nxt;
  }
  // powers 64..1024: feed U doubling
  const int um[5] = {1, 2, 4, 8, 16};
  for (int i = 0; i < 5; ++i) {
    int nxt = cur ^ 1;
    sq_mfma<<<gsq, 256, 0, stream>>>(S[cur][0], S[cur][1], S[cur][2], S[cur][3], S[cur][4], S[cur][5],
                                     Pz,
                                     S[nxt][0], S[nxt][1], S[nxt][2], S[nxt][3], S[nxt][4], S[nxt][5]);
    int M = um[i];
    rowgemm2<<<dim3(1, M, 8), 256, 0, stream>>>(U, Pz, U + (size_t)M * HDIM);
    cur = nxt;
  }

  wavedotK<<<dim3(512), 256, 0, stream>>>(U, Vc, Km);
  convk2<<<dim3(TLEN / 256, NBATCH), 256, 0, stream>>>(u, Km, Dv, out);
}

// Round 3
// 478.542 us; speedup vs baseline: 2.1167x; 1.0379x over previous
//
#include <hip/hip_runtime.h>

#define HDIM 1024
#define TLEN 2048
#define NBATCH 16

typedef short bf16x8 __attribute__((ext_vector_type(8)));
typedef float floatx4 __attribute__((ext_vector_type(4)));
typedef unsigned short ushort_t;

__device__ __forceinline__ ushort_t f2bf(float x) {
  unsigned u = __float_as_uint(x);
  unsigned r = (u + 0x7FFFu + ((u >> 16) & 1u)) >> 16;
  return (ushort_t)r;
}
__device__ __forceinline__ float bf2f(ushort_t h) {
  return __uint_as_float(((unsigned)h) << 16);
}

#define LSTR 40     // staged row stride in bf16 elems (32 + 8 pad)
#define TSTR 71     // epilogue transpose stride

// ---------------- prep: split A into bf16 h/m/l (+transposed) ; init V col0 / U row0 ----------------
__global__ __launch_bounds__(256) void prep(const float* __restrict__ A,
    const float* __restrict__ Bv, const float* __restrict__ Cv,
    ushort_t* __restrict__ Ah, ushort_t* __restrict__ Am, ushort_t* __restrict__ Al,
    ushort_t* __restrict__ ATh, ushort_t* __restrict__ ATm, ushort_t* __restrict__ ATl,
    float* __restrict__ Vc, float* __restrict__ U) {
  __shared__ ushort_t Lt[3 * 64 * TSTR];
  const int tid = threadIdx.x;
  if (blockIdx.x >= 256) {  // init blocks
    int i = (blockIdx.x - 256) * 256 + tid;
    if (i < HDIM) Vc[i] = Bv[i];
    else U[i - HDIM] = Cv[i - HDIM];
    return;
  }
  const int row0 = (blockIdx.x >> 4) * 64, col0 = (blockIdx.x & 15) * 64;
  const int r = tid >> 2, q = tid & 3;
  ushort_t hs[16], ms[16], ls[16];
#pragma unroll
  for (int c4 = 0; c4 < 4; ++c4) {
    float4 a = *(const float4*)&A[(row0 + r) * HDIM + col0 + q * 16 + c4 * 4];
    float av[4] = {a.x, a.y, a.z, a.w};
#pragma unroll
    for (int i = 0; i < 4; ++i) {
      float z = av[i];
      ushort_t h = f2bf(z); float r1 = z - bf2f(h);
      ushort_t mq = f2bf(r1); float r2 = r1 - bf2f(mq);
      ushort_t lq = f2bf(r2);
      hs[c4 * 4 + i] = h; ms[c4 * 4 + i] = mq; ls[c4 * 4 + i] = lq;
    }
  }
  size_t go = (size_t)(row0 + r) * HDIM + col0 + q * 16;
  *(uint4*)&Ah[go] = ((uint4*)hs)[0]; *(uint4*)&Ah[go + 8] = ((uint4*)hs)[1];
  *(uint4*)&Am[go] = ((uint4*)ms)[0]; *(uint4*)&Am[go + 8] = ((uint4*)ms)[1];
  *(uint4*)&Al[go] = ((uint4*)ls)[0]; *(uint4*)&Al[go + 8] = ((uint4*)ls)[1];
#pragma unroll
  for (int i = 0; i < 16; ++i) {
    int c = q * 16 + i;
    Lt[0 * 64 * TSTR + r * TSTR + c] = hs[i];
    Lt[1 * 64 * TSTR + r * TSTR + c] = ms[i];
    Lt[2 * 64 * TSTR + r * TSTR + c] = ls[i];
  }
  __syncthreads();
  const int c = tid >> 2, q2 = tid & 3;
  ushort_t* dsts[3] = {ATh, ATm, ATl};
#pragma unroll
  for (int s = 0; s < 3; ++s) {
    ushort_t tmp[16];
#pragma unroll
    for (int rr = 0; rr < 16; ++rr) tmp[rr] = Lt[s * 64 * TSTR + (q2 * 16 + rr) * TSTR + c];
    size_t gt = (size_t)(col0 + c) * HDIM + row0 + q2 * 16;
    *(uint4*)&dsts[s][gt] = ((uint4*)tmp)[0];
    *(uint4*)&dsts[s][gt + 8] = ((uint4*)tmp)[1];
  }
}

// ---------------- Z = X*X (bf16 3-split, 6 cross terms) + fused V/U-update tail ----------------
// MODE 0: tail computes Vc col 1 = A*Bv (fp32)
// MODE 1: tail computes Vc cols NC..2NC-1 = P * Vc cols 0..NC-1  (P = input power, h+m)
// MODE 2: tail computes U rows NC..2NC-1 = U rows 0..NC-1 * P    (via transposed splits, h+m)
template <int MODE, int NC>
__global__ __launch_bounds__(256) void sq_mfma(
    const ushort_t* __restrict__ Xh, const ushort_t* __restrict__ Xm,
    const ushort_t* __restrict__ Xl,
    const ushort_t* __restrict__ XTh, const ushort_t* __restrict__ XTm,
    const ushort_t* __restrict__ XTl,
    ushort_t* __restrict__ Zh, ushort_t* __restrict__ Zm, ushort_t* __restrict__ Zl,
    ushort_t* __restrict__ ZTh, ushort_t* __restrict__ ZTm, ushort_t* __restrict__ ZTl,
    const float* __restrict__ Af, const float* __restrict__ Bvf,
    float* __restrict__ VU) {
  __shared__ ushort_t sm[6 * 64 * LSTR];
  const int tid = threadIdx.x;

  if (blockIdx.x >= 16) {  // ---- tail blocks: 256 blocks -> 1024 waves ----
    const int tb = blockIdx.y * 16 + (blockIdx.x - 16);
    const int wv = tb * 4 + (tid >> 6);   // 0..1023
    const int lane = tid & 63;
    if (MODE == 0) {
      float acc = 0.f;
      for (int k = lane; k < HDIM; k += 64) acc += Af[(size_t)wv * HDIM + k] * Bvf[k];
      for (int off = 32; off; off >>= 1) acc += __shfl_down(acc, off);
      if (lane == 0) VU[HDIM + wv] = acc;
    } else {
      const ushort_t* Ph = (MODE == 1) ? Xh : XTh;
      const ushort_t* Pm = (MODE == 1) ? Xm : XTm;
      float acc[NC];
#pragma unroll
      for (int n = 0; n < NC; ++n) acc[n] = 0.f;
      for (int k = lane; k < HDIM; k += 64) {
        float a = bf2f(Ph[(size_t)wv * HDIM + k]) + bf2f(Pm[(size_t)wv * HDIM + k]);
#pragma unroll
        for (int n = 0; n < NC; ++n) acc[n] += a * VU[(size_t)n * HDIM + k];
      }
#pragma unroll
      for (int n = 0; n < NC; ++n) {
        float s = acc[n];
        for (int off = 32; off; off >>= 1) s += __shfl_down(s, off);
        if (lane == 0) VU[(size_t)(NC + n) * HDIM + wv] = s;
      }
    }
    return;
  }

  // ---- squaring blocks (16x16 tiles of 64x64) ----
  const int AH = 0, AM = 64 * LSTR, AL = 2 * 64 * LSTR;
  const int BH = 3 * 64 * LSTR, BM = 4 * 64 * LSTR, BL = 5 * 64 * LSTR;
  const int w = tid >> 6, l = tid & 63, li = l & 15, quad = l >> 4;
  const int row0 = blockIdx.y * 64, col0 = blockIdx.x * 64;
  const int sr = tid >> 2, sq4 = tid & 3;

  floatx4 acc0 = {0.f, 0.f, 0.f, 0.f}, acc1 = acc0, acc2 = acc0, acc3 = acc0;

  const int aoff = (w * 16 + li) * LSTR + quad * 8;
  const int b0o = (0 * 16 + li) * LSTR + quad * 8;
  const int b1o = (1 * 16 + li) * LSTR + quad * 8;
  const int b2o = (2 * 16 + li) * LSTR + quad * 8;
  const int b3o = (3 * 16 + li) * LSTR + quad * 8;
  const int soff = sr * LSTR + sq4 * 8;
  const size_t gA = (size_t)(row0 + sr) * HDIM + sq4 * 8;
  const size_t gB = (size_t)(col0 + sr) * HDIM + sq4 * 8;

  uint4 pa0 = *(const uint4*)&Xh[gA], pa1 = *(const uint4*)&Xm[gA], pa2 = *(const uint4*)&Xl[gA];
  uint4 pb0 = *(const uint4*)&XTh[gB], pb1 = *(const uint4*)&XTm[gB], pb2 = *(const uint4*)&XTl[gB];

  for (int k0 = 0; k0 < HDIM; k0 += 32) {
    __syncthreads();
    *(uint4*)&sm[AH + soff] = pa0;
    *(uint4*)&sm[AM + soff] = pa1;
    *(uint4*)&sm[AL + soff] = pa2;
    *(uint4*)&sm[BH + soff] = pb0;
    *(uint4*)&sm[BM + soff] = pb1;
    *(uint4*)&sm[BL + soff] = pb2;
    __syncthreads();
    if (k0 + 32 < HDIM) {
      pa0 = *(const uint4*)&Xh[gA + k0 + 32];
      pa1 = *(const uint4*)&Xm[gA + k0 + 32];
      pa2 = *(const uint4*)&Xl[gA + k0 + 32];
      pb0 = *(const uint4*)&XTh[gB + k0 + 32];
      pb1 = *(const uint4*)&XTm[gB + k0 + 32];
      pb2 = *(const uint4*)&XTl[gB + k0 + 32];
    }
    bf16x8 ah = *(const bf16x8*)&sm[AH + aoff];
    bf16x8 am = *(const bf16x8*)&sm[AM + aoff];
    bf16x8 al = *(const bf16x8*)&sm[AL + aoff];
    {
      bf16x8 bh = *(const bf16x8*)&sm[BH + b0o];
      bf16x8 bm = *(const bf16x8*)&sm[BM + b0o];
      bf16x8 bl = *(const bf16x8*)&sm[BL + b0o];
      acc0 = __builtin_amdgcn_mfma_f32_16x16x32_bf16(ah, bh, acc0, 0, 0, 0);
      acc0 = __builtin_amdgcn_mfma_f32_16x16x32_bf16(ah, bm, acc0, 0, 0, 0);
      acc0 = __builtin_amdgcn_mfma_f32_16x16x32_bf16(am, bh, acc0, 0, 0, 0);
      acc0 = __builtin_amdgcn_mfma_f32_16x16x32_bf16(am, bm, acc0, 0, 0, 0);
      acc0 = __builtin_amdgcn_mfma_f32_16x16x32_bf16(ah, bl, acc0, 0, 0, 0);
      acc0 = __builtin_amdgcn_mfma_f32_16x16x32_bf16(al, bh, acc0, 0, 0, 0);
    }
    {
      bf16x8 bh = *(const bf16x8*)&sm[BH + b1o];
      bf16x8 bm = *(const bf16x8*)&sm[BM + b1o];
      bf16x8 bl = *(const bf16x8*)&sm[BL + b1o];
      acc1 = __builtin_amdgcn_mfma_f32_16x16x32_bf16(ah, bh, acc1, 0, 0, 0);
      acc1 = __builtin_amdgcn_mfma_f32_16x16x32_bf16(ah, bm, acc1, 0, 0, 0);
      acc1 = __builtin_amdgcn_mfma_f32_16x16x32_bf16(am, bh, acc1, 0, 0, 0);
      acc1 = __builtin_amdgcn_mfma_f32_16x16x32_bf16(am, bm, acc1, 0, 0, 0);
      acc1 = __builtin_amdgcn_mfma_f32_16x16x32_bf16(ah, bl, acc1, 0, 0, 0);
      acc1 = __builtin_amdgcn_mfma_f32_16x16x32_bf16(al, bh, acc1, 0, 0, 0);
    }
    {
      bf16x8 bh = *(const bf16x8*)&sm[BH + b2o];
      bf16x8 bm = *(const bf16x8*)&sm[BM + b2o];
      bf16x8 bl = *(const bf16x8*)&sm[BL + b2o];
      acc2 = __builtin_amdgcn_mfma_f32_16x16x32_bf16(ah, bh, acc2, 0, 0, 0);
      acc2 = __builtin_amdgcn_mfma_f32_16x16x32_bf16(ah, bm, acc2, 0, 0, 0);
      acc2 = __builtin_amdgcn_mfma_f32_16x16x32_bf16(am, bh, acc2, 0, 0, 0);
      acc2 = __builtin_amdgcn_mfma_f32_16x16x32_bf16(am, bm, acc2, 0, 0, 0);
      acc2 = __builtin_amdgcn_mfma_f32_16x16x32_bf16(ah, bl, acc2, 0, 0, 0);
      acc2 = __builtin_amdgcn_mfma_f32_16x16x32_bf16(al, bh, acc2, 0, 0, 0);
    }
    {
      bf16x8 bh = *(const bf16x8*)&sm[BH + b3o];
      bf16x8 bm = *(const bf16x8*)&sm[BM + b3o];
      bf16x8 bl = *(const bf16x8*)&sm[BL + b3o];
      acc3 = __builtin_amdgcn_mfma_f32_16x16x32_bf16(ah, bh, acc3, 0, 0, 0);
      acc3 = __builtin_amdgcn_mfma_f32_16x16x32_bf16(ah, bm, acc3, 0, 0, 0);
      acc3 = __builtin_amdgcn_mfma_f32_16x16x32_bf16(am, bh, acc3, 0, 0, 0);
      acc3 = __builtin_amdgcn_mfma_f32_16x16x32_bf16(am, bm, acc3, 0, 0, 0);
      acc3 = __builtin_amdgcn_mfma_f32_16x16x32_bf16(ah, bl, acc3, 0, 0, 0);
      acc3 = __builtin_amdgcn_mfma_f32_16x16x32_bf16(al, bh, acc3, 0, 0, 0);
    }
  }

  // ---- epilogue: split result, write row-major + LDS-transposed splits ----
  __syncthreads();
  floatx4 accs[4] = {acc0, acc1, acc2, acc3};
#pragma unroll
  for (int j = 0; j < 4; ++j) {
#pragma unroll
    for (int e = 0; e < 4; ++e) {
      float z = accs[j][e];
      int rl = w * 16 + quad * 4 + e;
      int cl = j * 16 + li;
      size_t go = (size_t)(row0 + rl) * HDIM + col0 + cl;
      ushort_t h = f2bf(z); float r1 = z - bf2f(h);
      ushort_t mq = f2bf(r1); float r2 = r1 - bf2f(mq);
      ushort_t lq = f2bf(r2);
      Zh[go] = h; Zm[go] = mq; Zl[go] = lq;
      sm[0 * 64 * TSTR + rl * TSTR + cl] = h;
      sm[1 * 64 * TSTR + rl * TSTR + cl] = mq;
      sm[2 * 64 * TSTR + rl * TSTR + cl] = lq;
    }
  }
  __syncthreads();
  const int c = tid >> 2, q2 = tid & 3;
  ushort_t* dsts[3] = {ZTh, ZTm, ZTl};
#pragma unroll
  for (int s = 0; s < 3; ++s) {
    ushort_t tmp[16];
#pragma unroll
    for (int rr = 0; rr < 16; ++rr) tmp[rr] = sm[s * 64 * TSTR + (q2 * 16 + rr) * TSTR + c];
    size_t gt = (size_t)(col0 + c) * HDIM + row0 + q2 * 16;
    *(uint4*)&dsts[s][gt] = ((uint4*)tmp)[0];
    *(uint4*)&dsts[s][gt + 8] = ((uint4*)tmp)[1];
  }
}

// ---------------- final U-doubling: rows 16..31 = U[0:16] * A^1024 (transposed splits) ----------------
__global__ __launch_bounds__(256) void u_tail16(const ushort_t* __restrict__ PTh,
                                                const ushort_t* __restrict__ PTm,
                                                float* __restrict__ U) {
  const int wv = blockIdx.x * 4 + (threadIdx.x >> 6);
  const int lane = threadIdx.x & 63;
  float acc[16];
#pragma unroll
  for (int m = 0; m < 16; ++m) acc[m] = 0.f;
  for (int k = lane; k < HDIM; k += 64) {
    float a = bf2f(PTh[(size_t)wv * HDIM + k]) + bf2f(PTm[(size_t)wv * HDIM + k]);
#pragma unroll
    for (int m = 0; m < 16; ++m) acc[m] += a * U[(size_t)m * HDIM + k];
  }
#pragma unroll
  for (int m = 0; m < 16; ++m) {
    float s = acc[m];
    for (int off = 32; off; off >>= 1) s += __shfl_down(s, off);
    if (lane == 0) U[(size_t)(16 + m) * HDIM + wv] = s;
  }
}

// ---------------- K[m] = U row (m>>6) . V col (m&63) ----------------
__global__ __launch_bounds__(256) void wavedotK(const float* __restrict__ U,
                                                const float* __restrict__ Vc,
                                                float* __restrict__ Km) {
  int wv = (blockIdx.x * blockDim.x + threadIdx.x) >> 6;
  int lane = threadIdx.x & 63;
  if (wv >= 32 * 64) return;
  int mr = wv >> 6;
  int nc = wv & 63;
  float s = 0.f;
  for (int k = lane; k < HDIM; k += 64) s += U[mr * HDIM + k] * Vc[nc * HDIM + k];
  for (int off = 32; off; off >>= 1) s += __shfl_down(s, off);
  if (lane == 0) Km[wv] = s;
}

// ---------------- causal conv, LDS-tiled ----------------
__global__ __launch_bounds__(256) void convk2(const float* __restrict__ u,
                                              const float* __restrict__ Km,
                                              const float* __restrict__ Dv,
                                              float* __restrict__ y) {
  __shared__ float ks[256];
  __shared__ float us[512];
  const int tt = threadIdx.x;
  const int t0 = blockIdx.x * 256;
  const int b = blockIdx.y;
  const float* ub = u + (size_t)b * TLEN;
  const int t = t0 + tt;
  float s = Dv[0] * ub[t];
  for (int mc = 0; mc <= t0; mc += 256) {
    __syncthreads();
    ks[tt] = Km[mc + tt];
    int w0 = t0 - mc - 255;
    int g0 = w0 + tt;
    us[tt] = (g0 >= 0) ? ub[g0] : 0.f;
    int g1 = w0 + 256 + tt;
    us[256 + tt] = (g1 < TLEN) ? ub[g1] : 0.f;
    __syncthreads();
    if (mc < t0) {
#pragma unroll 4
      for (int r = 0; r < 256; r += 4) {
        float4 kv = *(const float4*)&ks[r];
        s += kv.x * us[tt - r + 255];
        s += kv.y * us[tt - r + 254];
        s += kv.z * us[tt - r + 253];
        s += kv.w * us[tt - r + 252];
      }
    } else {
      for (int r = 0; r <= tt; ++r) s += ks[r] * us[tt - r + 255];
    }
  }
  y[(size_t)b * TLEN + t] = s;
}

extern "C" void kernel_launch(void* const* d_in, const int* in_sizes, int n_in,
                              void* d_out, int out_size, void* d_ws, size_t ws_size,
                              hipStream_t stream) {
  const float* u  = (const float*)d_in[0];
  const float* A  = (const float*)d_in[1];
  const float* Bv = (const float*)d_in[2];
  const float* Cv = (const float*)d_in[3];
  const float* Dv = (const float*)d_in[4];
  float* out = (float*)d_out;

  char* wsb = (char*)d_ws;
  size_t off = 0;
  ushort_t* S[2][6];
  for (int s = 0; s < 2; ++s)
    for (int a = 0; a < 6; ++a) { S[s][a] = (ushort_t*)(wsb + off); off += (size_t)2 << 20; }
  float* Vc = (float*)(wsb + off); off += 64 * HDIM * 4;
  float* U  = (float*)(wsb + off); off += 32 * HDIM * 4;
  float* Km = (float*)(wsb + off); off += TLEN * 4;

  const dim3 gsq(32, 16);   // x<16: squaring tiles; x>=16: fused tail blocks

#define SQ(MODE, NC, IN, OUT, VU)                                              \
  sq_mfma<MODE, NC><<<gsq, 256, 0, stream>>>(                                  \
      S[IN][0], S[IN][1], S[IN][2], S[IN][3], S[IN][4], S[IN][5],              \
      S[OUT][0], S[OUT][1], S[OUT][2], S[OUT][3], S[OUT][4], S[OUT][5],        \
      A, Bv, VU)

  prep<<<dim3(264), 256, 0, stream>>>(A, Bv, Cv,
      S[0][0], S[0][1], S[0][2], S[0][3], S[0][4], S[0][5], Vc, U);

  SQ(0, 1,  0, 1, Vc);  // A^2    ; tail: V col1 = A*Bv (fp32)
  SQ(1, 2,  1, 0, Vc);  // A^4    ; tail: V cols 2,3   (A^2)
  SQ(1, 4,  0, 1, Vc);  // A^8    ; tail: V cols 4..7  (A^4)
  SQ(1, 8,  1, 0, Vc);  // A^16   ; tail: V cols 8..15 (A^8)
  SQ(1, 16, 0, 1, Vc);  // A^32   ; tail: V cols 16..31(A^16)
  SQ(1, 32, 1, 0, Vc);  // A^64   ; tail: V cols 32..63(A^32)
  SQ(2, 1,  0, 1, U);   // A^128  ; tail: U row 1      (A^64)
  SQ(2, 2,  1, 0, U);   // A^256  ; tail: U rows 2,3   (A^128)
  SQ(2, 4,  0, 1, U);   // A^512  ; tail: U rows 4..7  (A^256)
  SQ(2, 8,  1, 0, U);   // A^1024 ; tail: U rows 8..15 (A^512)
#undef SQ

  u_tail16<<<dim3(256), 256, 0, stream>>>(S[0][3], S[0][4], U);  // rows 16..31 (A^1024)
  wavedotK<<<dim3(512), 256, 0, stream>>>(U, Vc, Km);
  convk2<<<dim3(TLEN / 256, NBATCH), 256, 0, stream>>>(u, Km, Dv, out);
}